// Round 1
// baseline (201.846 us; speedup 1.0000x reference)
//
#include <hip/hip_runtime.h>
#include <hip/hip_bf16.h>

// Fused AdvancedHomeostaticCell: B=262144 rows, D_IN=D_OUT=128, fp32 in/out.
// Strategy: operand-swapped MFMA GEMMs (W as A, X/h_raw as B) so everything
// stays in registers; h_raw relayout for GEMM2 via v_permlane32_swap_b32.
// Zero LDS, zero barriers. Weights pre-cast to bf16 in d_ws by prep kernels.

typedef __attribute__((ext_vector_type(8)))  short short8;
typedef __attribute__((ext_vector_type(16))) float f32x16;

__device__ __forceinline__ unsigned short f2bf(float f) {
    union { float f; unsigned u; } v; v.f = f;
    unsigned r = v.u + 0x7fffu + ((v.u >> 16) & 1u);   // RNE
    return (unsigned short)(r >> 16);
}
__device__ __forceinline__ float bf2f(unsigned hs) {
    union { unsigned u; float f; } v; v.u = hs << 16;
    return v.f;
}
__device__ __forceinline__ unsigned pkbf(float lo, float hi) {
    return (unsigned)f2bf(lo) | ((unsigned)f2bf(hi) << 16);
}
__device__ __forceinline__ float sigm(float x) {
    return 1.0f / (1.0f + __expf(-x));
}
__device__ __forceinline__ float tanh_fast(float x) {
    return 1.0f - 2.0f / (1.0f + __expf(2.0f * x));
}
__device__ __forceinline__ f32x16 mfma_bf16(short8 a, short8 b, f32x16 c) {
    return __builtin_amdgcn_mfma_f32_32x32x16_bf16(a, b, c, 0, 0, 0);
}

// ---------- prep: cast weights to bf16 (Wcat = [Wi; Wf_x; Wslow+Wfast]) ----
__global__ void prep_weights(const float* __restrict__ Wi_w,
                             const float* __restrict__ Wf_w,
                             const float* __restrict__ Ws_w,
                             const float* __restrict__ Wfast_w,
                             const float* __restrict__ Wo_w,
                             unsigned short* __restrict__ Wcat,
                             unsigned short* __restrict__ Wo) {
    int gid = blockIdx.x * 256 + threadIdx.x;           // 0 .. 65535
    if (gid < 384 * 128) {
        int n = gid >> 7, k = gid & 127;
        float v;
        if (n < 128)      v = Wi_w[n * 128 + k];
        else if (n < 256) v = Wf_w[(n - 128) * 256 + k];          // x-half of Wf
        else              v = Ws_w[(n - 256) * 128 + k] + Wfast_w[(n - 256) * 128 + k];
        Wcat[gid] = f2bf(v);
    } else {
        int i = gid - 384 * 128;                        // < 16384
        Wo[i] = f2bf(Wo_w[i]);
    }
}

// fbias[j] = Wf_b[j] + sum_k Wf_w[j][128+k] * h_prev[k]   (hp part is batch-constant)
__global__ void prep_fbias(const float* __restrict__ Wf_w,
                           const float* __restrict__ Wf_b,
                           const float* __restrict__ hp,
                           float* __restrict__ fbias) {
    int j = threadIdx.x;                                // 128 threads
    float s = Wf_b[j];
    for (int k = 0; k < 128; ++k) s += Wf_w[j * 256 + 128 + k] * hp[k];
    fbias[j] = s;
}

// ------------------------------ main fused kernel --------------------------
__global__ __launch_bounds__(256, 2)
void cell_main(const float* __restrict__ x,
               const float* __restrict__ hp,
               const float* __restrict__ Wi_b,
               const float* __restrict__ Ws_b,
               const float* __restrict__ Wo_b,
               const float* __restrict__ ln_g,
               const float* __restrict__ ln_b,
               const unsigned short* __restrict__ Wcat,
               const unsigned short* __restrict__ Wo,
               const float* __restrict__ fbias,
               float* __restrict__ out) {
    const int tid  = threadIdx.x;
    const int lane = tid & 63;
    const int warp = tid >> 6;
    const int lm   = lane & 31;          // = m column within wave tile, also W row
    const int h    = lane >> 5;          // half-wave selector (k-block)
    const int wave_id = blockIdx.x * 4 + warp;
    const int m = wave_id * 32 + lm;     // this lane's batch row

    // --- preload this row's x as 8 bf16 B-fragments (k = 16*ks + 8*h + 0..7) ---
    short8 xf[8];
    const float* xrow = x + (size_t)m * 128 + h * 8;
    #pragma unroll
    for (int ks = 0; ks < 8; ++ks) {
        const float4 a = *(const float4*)(xrow + ks * 16);
        const float4 b = *(const float4*)(xrow + ks * 16 + 4);
        short8 v;
        v[0] = (short)f2bf(a.x); v[1] = (short)f2bf(a.y);
        v[2] = (short)f2bf(a.z); v[3] = (short)f2bf(a.w);
        v[4] = (short)f2bf(b.x); v[5] = (short)f2bf(b.y);
        v[6] = (short)f2bf(b.z); v[7] = (short)f2bf(b.w);
        xf[ks] = v;
    }

    // --- GEMM1: D[n, m] for n in 4 groups of 32; gates i/f/s fused ---
    // acc layout (32x32x16): col = lane&31 (=m), row_local = (r&3)+8*(r>>2)+4*h
    unsigned hpk[32];                    // h_raw packed bf16 pairs, per-lane column m
    #pragma unroll
    for (int jg = 0; jg < 4; ++jg) {
        f32x16 acc_i, acc_f, acc_s;
        #pragma unroll
        for (int e = 0; e < 16; ++e) { acc_i[e] = 0.f; acc_f[e] = 0.f; acc_s[e] = 0.f; }
        const unsigned short* Wg = Wcat + (size_t)(jg * 32 + lm) * 128 + h * 8;
        #pragma unroll
        for (int ks = 0; ks < 8; ++ks) {
            const short8 wi = *(const short8*)(const void*)(Wg + ks * 16);
            const short8 wf = *(const short8*)(const void*)(Wg + 128 * 128 + ks * 16);
            const short8 ws = *(const short8*)(const void*)(Wg + 256 * 128 + ks * 16);
            acc_i = mfma_bf16(wi, xf[ks], acc_i);
            acc_f = mfma_bf16(wf, xf[ks], acc_f);
            acc_s = mfma_bf16(ws, xf[ks], acc_s);
        }
        #pragma unroll
        for (int q = 0; q < 4; ++q) {
            const int n0 = jg * 32 + q * 8 + h * 4;     // 4 consecutive n per reg quad
            const float4 bi = *(const float4*)(Wi_b + n0);
            const float4 bf = *(const float4*)(fbias + n0);
            const float4 bs = *(const float4*)(Ws_b + n0);
            const float4 bh = *(const float4*)(hp + n0);
            float iv, fv, sv, h0, h1, h2, h3;
            iv = sigm(acc_i[q*4+0] + bi.x); fv = sigm(acc_f[q*4+0] + bf.x);
            sv = acc_s[q*4+0] + bs.x;       h0 = iv * sv + fv * bh.x;
            iv = sigm(acc_i[q*4+1] + bi.y); fv = sigm(acc_f[q*4+1] + bf.y);
            sv = acc_s[q*4+1] + bs.y;       h1 = iv * sv + fv * bh.y;
            iv = sigm(acc_i[q*4+2] + bi.z); fv = sigm(acc_f[q*4+2] + bf.z);
            sv = acc_s[q*4+2] + bs.z;       h2 = iv * sv + fv * bh.z;
            iv = sigm(acc_i[q*4+3] + bi.w); fv = sigm(acc_f[q*4+3] + bf.w);
            sv = acc_s[q*4+3] + bs.w;       h3 = iv * sv + fv * bh.w;
            // pack pairs ordered by n: pair p holds n = 8*(p>>1) + 2*(p&1) + 4h (lo,hi)
            hpk[jg * 8 + q * 2 + 0] = pkbf(h0, h1);
            hpk[jg * 8 + q * 2 + 1] = pkbf(h2, h3);
        }
    }

    // --- GEMM2: D[n2, m] = sum_k Wo[n2,k] * h_raw[k, m]; B rebuilt via permlane ---
    f32x16 oacc[4];
    #pragma unroll
    for (int T = 0; T < 4; ++T)
        #pragma unroll
        for (int e = 0; e < 16; ++e) oacc[T][e] = 0.f;

    #pragma unroll
    for (int ks = 0; ks < 8; ++ks) {
        unsigned c0 = hpk[4*ks+0], c1 = hpk[4*ks+1], c2 = hpk[4*ks+2], c3 = hpk[4*ks+3];
        // swap: after, c0 = {own.lo, c2.lo}, c2 = {c0.hi, own.hi} -> each lane gets
        // exactly the 8 consecutive k-values (16ks + 8h + 0..7) for its column m.
        asm volatile("v_permlane32_swap_b32 %0, %1" : "+v"(c0), "+v"(c2));
        asm volatile("v_permlane32_swap_b32 %0, %1" : "+v"(c1), "+v"(c3));
        union { unsigned u[4]; short8 s8; } bb;
        bb.u[0] = c0; bb.u[1] = c1; bb.u[2] = c2; bb.u[3] = c3;
        #pragma unroll
        for (int T = 0; T < 4; ++T) {
            const short8 wfrag = *(const short8*)(const void*)
                (Wo + (size_t)(T * 32 + lm) * 128 + ks * 16 + h * 8);
            oacc[T] = mfma_bf16(wfrag, bb.s8, oacc[T]);
        }
    }

    // --- epilogue: o_t, h_out, LayerNorm over the 128 features of row m ---
    float hout[64];
    float sum = 0.f, ssq = 0.f;
    #pragma unroll
    for (int T = 0; T < 4; ++T) {
        #pragma unroll
        for (int q = 0; q < 4; ++q) {
            const int n0 = T * 32 + q * 8 + h * 4;
            const float4 bo = *(const float4*)(Wo_b + n0);
            #pragma unroll
            for (int rr = 0; rr < 4; ++rr) {
                const int p = T * 8 + q * 2 + (rr >> 1);
                const unsigned u = hpk[p];
                const float hr = bf2f((rr & 1) ? (u >> 16) : (u & 0xffffu));
                const float bov = (rr == 0) ? bo.x : (rr == 1) ? bo.y : (rr == 2) ? bo.z : bo.w;
                const float ov = sigm(oacc[T][q * 4 + rr] + bov);
                const float hv = ov * tanh_fast(hr);
                hout[T * 16 + q * 4 + rr] = hv;
                sum += hv; ssq += hv * hv;
            }
        }
    }
    sum += __shfl_xor(sum, 32, 64);      // partner half-wave holds the other 64 features
    ssq += __shfl_xor(ssq, 32, 64);
    const float mean = sum * (1.0f / 128.0f);
    const float var  = ssq * (1.0f / 128.0f) - mean * mean;
    const float rstd = rsqrtf(var + 1e-5f);

    float* orow = out + (size_t)m * 128;
    #pragma unroll
    for (int T = 0; T < 4; ++T) {
        #pragma unroll
        for (int q = 0; q < 4; ++q) {
            const int n0 = T * 32 + q * 8 + h * 4;
            const float4 g4 = *(const float4*)(ln_g + n0);
            const float4 b4 = *(const float4*)(ln_b + n0);
            float4 r;
            r.x = (hout[T*16+q*4+0] - mean) * rstd * g4.x + b4.x;
            r.y = (hout[T*16+q*4+1] - mean) * rstd * g4.y + b4.y;
            r.z = (hout[T*16+q*4+2] - mean) * rstd * g4.z + b4.z;
            r.w = (hout[T*16+q*4+3] - mean) * rstd * g4.w + b4.w;
            *(float4*)(orow + n0) = r;
        }
    }
}

// ------------------------------- launch ------------------------------------
extern "C" void kernel_launch(void* const* d_in, const int* in_sizes, int n_in,
                              void* d_out, int out_size, void* d_ws, size_t ws_size,
                              hipStream_t stream) {
    const float* x      = (const float*)d_in[0];
    const float* h_prev = (const float*)d_in[1];
    const float* Ws_w   = (const float*)d_in[2];
    const float* Ws_b   = (const float*)d_in[3];
    const float* Wfast  = (const float*)d_in[4];
    const float* Wi_w   = (const float*)d_in[5];
    const float* Wi_b   = (const float*)d_in[6];
    const float* Wf_w   = (const float*)d_in[7];
    const float* Wf_b   = (const float*)d_in[8];
    const float* Wo_w   = (const float*)d_in[9];
    const float* Wo_b   = (const float*)d_in[10];
    const float* ln_g   = (const float*)d_in[11];
    const float* ln_b   = (const float*)d_in[12];

    unsigned short* Wcat = (unsigned short*)d_ws;            // 384*128 bf16
    unsigned short* Wo   = Wcat + 384 * 128;                 // 128*128 bf16
    float*          fb   = (float*)(Wo + 128 * 128);         // 128 f32

    prep_weights<<<256, 256, 0, stream>>>(Wi_w, Wf_w, Ws_w, Wfast, Wo_w, Wcat, Wo);
    prep_fbias<<<1, 128, 0, stream>>>(Wf_w, Wf_b, h_prev, fb);

    const int B = in_sizes[0] / 128;                         // 262144
    const int blocks = B / 128;                              // 4 waves * 32 rows
    cell_main<<<blocks, 256, 0, stream>>>(x, h_prev, Wi_b, Ws_b, Wo_b,
                                          ln_g, ln_b, Wcat, Wo, fb,
                                          (float*)d_out);
}